// Round 11
// baseline (559.231 us; speedup 1.0000x reference)
//
#include <hip/hip_runtime.h>
#include <cmath>

#define N_TOK 196
#define NPX   38416
#define CDIM  256

typedef _Float16 f16;
typedef __attribute__((ext_vector_type(8))) _Float16 half8;
typedef __attribute__((ext_vector_type(4))) float f32x4;

// ---------------------------------------------------------------------------
// Projection GEMM via fp16 MFMA, split-K=8. M=1568, N=256, K=2048.
// Tile 128m x 128n, K-step 32, inline fp32->f16 staging. grid (2, 13, 8).
// ---------------------------------------------------------------------------
__global__ __launch_bounds__(256) void proj_mfma(
    const float* __restrict__ A,   // x  [1568][2048]
    const float* __restrict__ B,   // w_prj [2048][256]
    float* __restrict__ P)         // [8][1568][256]
{
    __shared__ f16 As[128 * 40];   // [m][k] pad 40 (16B-aligned rows)
    __shared__ f16 Bs[128 * 40];   // [n][k] (transposed during staging)
    int tid = threadIdx.x;
    int n0 = blockIdx.x * 128, m0 = blockIdx.y * 128;
    int kz = blockIdx.z;
    int wave = tid >> 6, lane = tid & 63;
    int quad = lane >> 4, l16 = lane & 15;

    f32x4 zero = {0.f, 0.f, 0.f, 0.f};
    f32x4 acc[2][8];
    #pragma unroll
    for (int mt = 0; mt < 2; ++mt)
        #pragma unroll
        for (int nt = 0; nt < 8; ++nt) acc[mt][nt] = zero;

    for (int k0 = kz * 256; k0 < kz * 256 + 256; k0 += 32) {
        __syncthreads();
        #pragma unroll
        for (int s = 0; s < 4; ++s) {
            int idx = tid + s * 256;
            int m = idx >> 3, kq = idx & 7;
            int gm = m0 + m;
            float4 v = make_float4(0.f, 0.f, 0.f, 0.f);
            if (gm < 1568) v = *(const float4*)(A + (size_t)gm * 2048 + k0 + kq * 4);
            f16* d = As + m * 40 + kq * 4;
            d[0] = (f16)v.x; d[1] = (f16)v.y; d[2] = (f16)v.z; d[3] = (f16)v.w;
        }
        #pragma unroll
        for (int s = 0; s < 4; ++s) {
            int idx = tid + s * 256;
            int nq = idx & 31, kk = idx >> 5;
            float4 v = *(const float4*)(B + (size_t)(k0 + kk) * 256 + n0 + nq * 4);
            Bs[(nq * 4 + 0) * 40 + kk] = (f16)v.x;
            Bs[(nq * 4 + 1) * 40 + kk] = (f16)v.y;
            Bs[(nq * 4 + 2) * 40 + kk] = (f16)v.z;
            Bs[(nq * 4 + 3) * 40 + kk] = (f16)v.w;
        }
        __syncthreads();
        half8 a[2];
        #pragma unroll
        for (int mt = 0; mt < 2; ++mt)
            a[mt] = *(const half8*)(As + (wave * 32 + mt * 16 + l16) * 40 + quad * 8);
        #pragma unroll
        for (int nt = 0; nt < 8; ++nt) {
            half8 bf = *(const half8*)(Bs + (nt * 16 + l16) * 40 + quad * 8);
            acc[0][nt] = __builtin_amdgcn_mfma_f32_16x16x32_f16(a[0], bf, acc[0][nt], 0, 0, 0);
            acc[1][nt] = __builtin_amdgcn_mfma_f32_16x16x32_f16(a[1], bf, acc[1][nt], 0, 0, 0);
        }
    }
    float* Pz = P + (size_t)kz * 401408;
    #pragma unroll
    for (int mt = 0; mt < 2; ++mt) {
        #pragma unroll
        for (int nt = 0; nt < 8; ++nt) {
            int gn = n0 + nt * 16 + l16;
            #pragma unroll
            for (int r = 0; r < 4; ++r) {
                int gm = m0 + wave * 32 + mt * 16 + quad * 4 + r;
                if (gm < 1568) Pz[(size_t)gm * 256 + gn] = acc[mt][nt][r];
            }
        }
    }
}

// sum 8 K-slices + bias -> fp16 sub
__global__ void reduce_subh(const float* __restrict__ P,
                            const float* __restrict__ bias,
                            f16* __restrict__ subh)
{
    int e = blockIdx.x * 256 + threadIdx.x;
    if (e >= 401408) return;
    float s = bias[e & 255];
    #pragma unroll
    for (int z = 0; z < 8; ++z) s += P[(size_t)z * 401408 + e];
    subh[e] = (f16)s;
}

// ---------------------------------------------------------------------------
// w [tap][Kc][D] fp32 -> wt [tap][D][Kc] fp16  (plain transpose, branch0)
// ---------------------------------------------------------------------------
__global__ void cvt_wt(const float* __restrict__ w, f16* __restrict__ wt,
                       int Kc, int D, int total)
{
    int e = blockIdx.x * 256 + threadIdx.x;
    if (e >= total) return;
    int td = Kc * D;
    int tap = e / td, r = e - tap * td;
    int c = r / D, d = r - c * D;
    wt[(size_t)(tap * D + d) * Kc + c] = (f16)w[e];
}

// ---------------------------------------------------------------------------
// w [tap][Kc][D] fp32 -> MFMA B-fragment-packed fp16:
// wf[(((tap*tiles + tile)*kch + k)*64 + lane)*8 + j], lane=(quad*16+l16),
// element = w[tap][k*32 + quad*8 + j][tile*16 + l16].
// ---------------------------------------------------------------------------
__global__ void cvt_wfrag(const float* __restrict__ w, f16* __restrict__ wf,
                          int Kc, int D, int taps)
{
    int tiles = D >> 4, kch = Kc >> 5;
    int total = taps * tiles * kch * 64;
    int e = blockIdx.x * 256 + threadIdx.x;
    if (e >= total) return;
    int lane = e & 63;
    int rest = e >> 6;
    int k = rest % kch; rest /= kch;
    int tile = rest % tiles;
    int tap = rest / tiles;
    int l16 = lane & 15, quad = lane >> 4;
    const float* src = w + ((size_t)tap * Kc + k * 32 + quad * 8) * D + tile * 16 + l16;
    f16* dst = wf + (size_t)e * 8;
    #pragma unroll
    for (int j = 0; j < 8; ++j) dst[j] = (f16)src[(size_t)j * D];
}

// x [b][196][2048] fp32 -> xht [b][2048][200] fp16 (k-pad 200, zeros)
__global__ __launch_bounds__(256) void cvt_xT(const float* __restrict__ x,
                                              f16* __restrict__ xht)
{
    __shared__ float t[32][33];
    int b = blockIdx.z;
    int i0 = blockIdx.y * 32, n0 = blockIdx.x * 32;
    const float* xb = x + (size_t)b * 196 * 2048;
    for (int e = threadIdx.x; e < 1024; e += 256) {
        int r = e >> 5, c = e & 31;
        int gi = i0 + r;
        t[r][c] = (gi < 196) ? xb[(size_t)gi * 2048 + n0 + c] : 0.f;
    }
    __syncthreads();
    f16* xb2 = xht + (size_t)b * 2048 * 200;
    for (int e = threadIdx.x; e < 1024; e += 256) {
        int nl = e >> 5, il = e & 31;
        int gi = i0 + il, gn = n0 + nl;
        if (gi < 200) xb2[(size_t)gn * 200 + gi] = (f16)t[il][nl];
    }
}

// ---------------------------------------------------------------------------
// Conv1 v8: occupancy retile. Same 8i x 32j x 128d block tile, same LDS,
// same dedup K-loop, but 16 waves of 2i x 32j px x 32d (acc = 8 f32x4 = 32
// AGPR; target <=128 total regs -> 4 waves/SIMD vs v6's 2). grid (7, 25, 8),
// block 1024.
// ---------------------------------------------------------------------------
__global__ __launch_bounds__(1024, 4) void conv1_mfma(
    const f16* __restrict__ sub_h,   // [8][196][256]
    const f16* __restrict__ w1f,     // frag-packed [9][8][8][64][8]
    const float* __restrict__ b1,    // [128]
    f16* __restrict__ Y1h)           // [8][196][196][128]
{
    __shared__ f16 sh[17408];        // 34816 B
    f16* SJ = sh;                    // [34][264] rows j0-1..j0+32
    f16* SI = sh + 8976;             // [10][264] rows i0-1..i0+8
    f16* OT = sh;                    // epilogue [128][136] (aliases SJ/SI)

    int b = blockIdx.z;
    int i0 = blockIdx.y * 8, j0 = blockIdx.x * 32;
    int tid = threadIdx.x;
    const f16* subB = sub_h + (size_t)b * N_TOK * CDIM;

    uint4 zz = make_uint4(0, 0, 0, 0);
    for (int e = tid; e < 1088; e += 1024) {      // SJ
        int r = e >> 5, q = e & 31;
        int gj = j0 - 1 + r;
        uint4 v = zz;
        if (gj >= 0 && gj < N_TOK) v = *(const uint4*)(subB + gj * CDIM + q * 8);
        *(uint4*)(SJ + r * 264 + q * 8) = v;
    }
    for (int e = tid; e < 320; e += 1024) {       // SI
        int r = e >> 5, q = e & 31;
        int gi = i0 - 1 + r;
        uint4 v = zz;
        if (gi >= 0 && gi < N_TOK) v = *(const uint4*)(subB + gi * CDIM + q * 8);
        *(uint4*)(SI + r * 264 + q * 8) = v;
    }
    __syncthreads();

    int wave = tid >> 6, lane = tid & 63;
    int quad = lane >> 4, l16 = lane & 15;
    int ig = wave >> 2;          // i-group: output rows ig*2 .. ig*2+1
    int dg = wave & 3;           // d-group: d0 = dg*32
    int d0 = dg * 32;

    float bias_r[2];
    #pragma unroll
    for (int n = 0; n < 2; ++n) bias_r[n] = b1[d0 + n * 16 + l16];

    // frag strides (halfs): lane 8, k 512, tile 4096, tap 32768
    const f16* wbase = w1f + (size_t)lane * 8 + (size_t)dg * 2 * 4096;

    // per-(block,wave) k-phase rotation (uniform scalar; bijective over k)
    int lb = blockIdx.x + 7 * (blockIdx.y + 25 * blockIdx.z);
    int rot = (lb * 5 + wave) & 7;

    f32x4 zero = {0.f, 0.f, 0.f, 0.f};
    f32x4 acc[4][2];             // [m*2+jf][n], m in {0,1}
    #pragma unroll
    for (int a = 0; a < 4; ++a)
        #pragma unroll
        for (int n = 0; n < 2; ++n) acc[a][n] = zero;

    for (int kk = 0; kk < 8; ++kk) {
        int k = (kk + rot) & 7;
        int c0 = k * 32;
        half8 si[4];
        #pragma unroll
        for (int r = 0; r < 4; ++r)
            si[r] = *(const half8*)(SI + (ig * 2 + r) * 264 + c0 + quad * 8);

        #pragma unroll
        for (int dj = 0; dj < 3; ++dj) {
            half8 sj0 = *(const half8*)(SJ + (l16 + dj) * 264 + c0 + quad * 8);
            half8 sj1 = *(const half8*)(SJ + (16 + l16 + dj) * 264 + c0 + quad * 8);
            half8 bf[3][2];
            #pragma unroll
            for (int di = 0; di < 3; ++di)
                #pragma unroll
                for (int n = 0; n < 2; ++n)
                    bf[di][n] = *(const half8*)(wbase + (size_t)(di * 3 + dj) * 32768
                                                + n * 4096 + k * 512);
            #pragma unroll
            for (int r = 0; r < 4; ++r) {
                half8 a0 = si[r] * sj0;
                half8 a1 = si[r] * sj1;
                #pragma unroll
                for (int di = 0; di < 3; ++di) {
                    int m = r - di;
                    if (m < 0 || m > 1) continue;
                    #pragma unroll
                    for (int n = 0; n < 2; ++n) {
                        acc[m * 2 + 0][n] = __builtin_amdgcn_mfma_f32_16x16x32_f16(
                            a0, bf[di][n], acc[m * 2 + 0][n], 0, 0, 0);
                        acc[m * 2 + 1][n] = __builtin_amdgcn_mfma_f32_16x16x32_f16(
                            a1, bf[di][n], acc[m * 2 + 1][n], 0, 0, 0);
                    }
                }
            }
        }
    }

    // epilogue: two px-half phases through OT (aliases SJ/SI)
    __syncthreads();
    f16* Yb = Y1h + (size_t)b * NPX * 128;
    #pragma unroll
    for (int ph = 0; ph < 2; ++ph) {
        if ((ig >> 1) == ph) {
            #pragma unroll
            for (int m = 0; m < 2; ++m)
                #pragma unroll
                for (int jf = 0; jf < 2; ++jf) {
                    int al = m * 2 + jf;
                    int il = ig * 2 + m - ph * 4;      // 0..3 within phase
                    #pragma unroll
                    for (int n = 0; n < 2; ++n) {
                        int dl = d0 + n * 16 + l16;
                        #pragma unroll
                        for (int r = 0; r < 4; ++r) {
                            int pxl = il * 32 + jf * 16 + quad * 4 + r;
                            OT[pxl * 136 + dl] = (f16)fmaxf(acc[al][n][r] + bias_r[n], 0.f);
                        }
                    }
                }
        }
        __syncthreads();
        for (int e = tid; e < 2048; e += 1024) {
            int pxl = e >> 4, q = e & 15;
            int gi = i0 + ph * 4 + (pxl >> 5), gj = j0 + (pxl & 31);
            if (gi < N_TOK && gj < N_TOK)
                *(uint4*)(Yb + ((size_t)gi * N_TOK + gj) * 128 + q * 8) =
                    *(const uint4*)(OT + pxl * 136 + q * 8);
        }
        __syncthreads();
    }
}

// ---------------------------------------------------------------------------
// Conv2 v3: 3x3 dil (1,2), 128->64, frag-packed B, barrier-free K-loop.
// Tile 128px (4i x 32j) x 64d, 4 waves; wave = 1 i-row x 32j (2 j-frags).
// Halo read-amplification 1.69x. grid (7, 49, 8).
// ---------------------------------------------------------------------------
__global__ __launch_bounds__(256, 2) void conv2_mfma(
    const f16* __restrict__ Y1h, const f16* __restrict__ w2f,
    const float* __restrict__ b2, f16* __restrict__ Y2h)
{
    __shared__ f16 sh[29376];        // [6][36][136] = 58752 B
    f16* Ys = sh;
    f16* OT = sh;                    // epilogue [128][72] (aliases Ys)

    int b = blockIdx.z;
    int i0 = blockIdx.y * 4, j0 = blockIdx.x * 32;
    int tid = threadIdx.x;
    const f16* Yb = Y1h + (size_t)b * NPX * 128;

    uint4 zz = make_uint4(0, 0, 0, 0);
    for (int e = tid; e < 3456; e += 256) {
        int ir = e / 576, rem = e - ir * 576;
        int jq = rem >> 4, q = rem & 15;
        int gi = i0 - 1 + ir, gj = j0 - 2 + jq;
        uint4 v = zz;
        if (gi >= 0 && gi < N_TOK && gj >= 0 && gj < N_TOK)
            v = *(const uint4*)(Yb + ((size_t)gi * N_TOK + gj) * 128 + q * 8);
        *(uint4*)(Ys + (ir * 36 + jq) * 136 + q * 8) = v;
    }
    __syncthreads();

    int wave = tid >> 6, lane = tid & 63;
    int quad = lane >> 4, l16 = lane & 15;
    int ii = wave;                   // i-row within tile

    // frag strides (halfs): lane 8, k 512, tile 2048, tap 8192
    const f16* wbase = w2f + (size_t)lane * 8;

    f32x4 zero = {0.f, 0.f, 0.f, 0.f};
    f32x4 acc[2][4];
    #pragma unroll
    for (int jf = 0; jf < 2; ++jf)
        #pragma unroll
        for (int n = 0; n < 4; ++n) acc[jf][n] = zero;

    #pragma unroll
    for (int tap = 0; tap < 9; ++tap) {
        int di = tap / 3 - 1, dj2 = (tap % 3 - 1) * 2;
        #pragma unroll
        for (int k = 0; k < 4; ++k) {
            int c0 = k * 32;
            half8 a0 = *(const half8*)(Ys + ((ii + di + 1) * 36 + l16 + dj2 + 2) * 136
                                       + c0 + quad * 8);
            half8 a1 = *(const half8*)(Ys + ((ii + di + 1) * 36 + 16 + l16 + dj2 + 2) * 136
                                       + c0 + quad * 8);
            #pragma unroll
            for (int n = 0; n < 4; ++n) {
                half8 bf = *(const half8*)(wbase + (size_t)tap * 8192 + n * 2048 + k * 512);
                acc[0][n] = __builtin_amdgcn_mfma_f32_16x16x32_f16(a0, bf, acc[0][n], 0, 0, 0);
                acc[1][n] = __builtin_amdgcn_mfma_f32_16x16x32_f16(a1, bf, acc[1][n], 0, 0, 0);
            }
        }
    }
    __syncthreads();
    #pragma unroll
    for (int jf = 0; jf < 2; ++jf)
        #pragma unroll
        for (int n = 0; n < 4; ++n) {
            int d = n * 16 + l16;
            float bias = b2[d];
            #pragma unroll
            for (int r = 0; r < 4; ++r) {
                int px = ii * 32 + jf * 16 + quad * 4 + r;
                OT[px * 72 + d] = (f16)fmaxf(acc[jf][n][r] + bias, 0.f);
            }
        }
    __syncthreads();
    f16* Zb = Y2h + (size_t)b * NPX * 64;
    for (int e = tid; e < 1024; e += 256) {
        int px = e >> 3, q = e & 7;
        int i = i0 + (px >> 5), j = j0 + (px & 31);
        if (j < N_TOK)
            *(uint4*)(Zb + ((size_t)i * N_TOK + j) * 64 + q * 8) =
                *(const uint4*)(OT + px * 72 + q * 8);
    }
}

// ---------------------------------------------------------------------------
// Conv3 v2: LDS-staged. Block = 8i x 32j px, halo'd tile [10][40][64] (pad 68).
// Lanes split 8-per-px over c (2-way bank aliasing = free), shfl reduce.
// grid (7, 25, 8).
// ---------------------------------------------------------------------------
__global__ __launch_bounds__(256) void conv3_s(
    const f16* __restrict__ Y2h, const float* __restrict__ w3,
    const float* __restrict__ b3, float* __restrict__ X1)
{
    __shared__ f16 Ys[10 * 40 * 68];   // 54400 B
    __shared__ float ws[576];
    int b = blockIdx.z;
    int i0 = blockIdx.y * 8, j0 = blockIdx.x * 32;
    int tid = threadIdx.x;
    const f16* Yb = Y2h + (size_t)b * NPX * 64;
    for (int e = tid; e < 576; e += 256) ws[e] = w3[e];
    uint4 zz = make_uint4(0, 0, 0, 0);
    for (int e = tid; e < 3200; e += 256) {
        int r = e / 320, rem = e - r * 320;
        int jq = rem >> 3, q = rem & 7;
        int gi = i0 - 1 + r, gj = j0 - 4 + jq;
        uint4 v = zz;
        if (gi >= 0 && gi < N_TOK && gj >= 0 && gj < N_TOK)
            v = *(const uint4*)(Yb + ((size_t)gi * N_TOK + gj) * 64 + q * 8);
        *(uint4*)(Ys + (r * 40 + jq) * 68 + q * 8) = v;
    }
    __syncthreads();
    int q = tid & 7, jl = (tid >> 3) & 31;
    float* Xb = X1 + (size_t)b * NPX;
    float bb = b3[0];
    #pragma unroll
    for (int il = 0; il < 8; ++il) {
        float s = 0.f;
        #pragma unroll
        for (int tap = 0; tap < 9; ++tap) {
            int di = tap / 3 - 1, dj4 = (tap % 3 - 1) * 4;
            half8 h = *(const half8*)(Ys + ((il + 1 + di) * 40 + jl + 4 + dj4) * 68 + q * 8);
            #pragma unroll
            for (int e = 0; e < 8; ++e) s += (float)h[e] * ws[tap * 64 + q * 8 + e];
        }
        s += __shfl_xor(s, 1);
        s += __shfl_xor(s, 2);
        s += __shfl_xor(s, 4);
        if (q == 0) {
            int gi = i0 + il, gj = j0 + jl;
            if (gi < N_TOK && gj < N_TOK)
                Xb[gi * N_TOK + gj] = fmaxf(s + bb, 0.f);
        }
    }
}

// ---------------------------------------------------------------------------
// Branch 0 MFMA: pair -> 1x1 stack 256->128->64->1, all in one block.
// ---------------------------------------------------------------------------
__global__ __launch_bounds__(256, 2) void branch0_mfma(
    const f16* __restrict__ sub_h,
    const f16* __restrict__ w01t,    // [128][256]
    const float* __restrict__ b01,
    const f16* __restrict__ w02t,    // [64][128]
    const float* __restrict__ b02,
    const float* __restrict__ w03, const float* __restrict__ b03,
    float* __restrict__ X0)
{
    __shared__ f16 sh[32000];
    __shared__ float W3s[64];
    f16* SJ = sh;            // [32][264]
    f16* SI = sh + 8448;     // [4][256]
    f16* BW = sh + 9472;     // [128][40]
    f16* H1 = sh + 14592;    // [128][136]
    f16* H2 = sh;            // [128][72] (aliases SJ/SI)

    int b = blockIdx.z;
    int i0 = blockIdx.y * 4, j0 = blockIdx.x * 32;
    int tid = threadIdx.x;
    const f16* subB = sub_h + (size_t)b * N_TOK * CDIM;

    uint4 zz = make_uint4(0, 0, 0, 0);
    for (int e = tid; e < 1024; e += 256) {
        int r = e >> 5, q = e & 31;
        int gj = j0 + r;
        uint4 v = zz;
        if (gj < N_TOK) v = *(const uint4*)(subB + gj * CDIM + q * 8);
        *(uint4*)(SJ + r * 264 + q * 8) = v;
    }
    if (tid < 128) {
        int r = tid >> 5, q = tid & 31;
        int gi = i0 + r;
        uint4 v = zz;
        if (gi < N_TOK) v = *(const uint4*)(subB + gi * CDIM + q * 8);
        *(uint4*)(SI + r * 256 + q * 8) = v;
    }
    if (tid < 64) W3s[tid] = w03[tid];

    int wave = tid >> 6, lane = tid & 63;
    int quad = lane >> 4, l16 = lane & 15;
    int ii = wave;

    f32x4 zero = {0.f, 0.f, 0.f, 0.f};
    f32x4 acc[2][8];
    #pragma unroll
    for (int t = 0; t < 2; ++t)
        #pragma unroll
        for (int n = 0; n < 8; ++n) acc[t][n] = zero;

    for (int c0 = 0; c0 < 256; c0 += 32) {
        __syncthreads();
        for (int e = tid; e < 512; e += 256) {
            int d = e >> 2, q = e & 3;
            *(uint4*)(BW + d * 40 + q * 8) =
                *(const uint4*)(w01t + (size_t)d * 256 + c0 + q * 8);
        }
        __syncthreads();
        half8 sib = *(const half8*)(SI + ii * 256 + c0 + quad * 8);
        half8 a0 = sib * *(const half8*)(SJ + l16 * 264 + c0 + quad * 8);
        half8 a1 = sib * *(const half8*)(SJ + (l16 + 16) * 264 + c0 + quad * 8);
        #pragma unroll
        for (int n = 0; n < 8; ++n) {
            half8 bf = *(const half8*)(BW + (n * 16 + l16) * 40 + quad * 8);
            acc[0][n] = __builtin_amdgcn_mfma_f32_16x16x32_f16(a0, bf, acc[0][n], 0, 0, 0);
            acc[1][n] = __builtin_amdgcn_mfma_f32_16x16x32_f16(a1, bf, acc[1][n], 0, 0, 0);
        }
    }
    #pragma unroll
    for (int t = 0; t < 2; ++t)
        #pragma unroll
        for (int n = 0; n < 8; ++n) {
            int d = n * 16 + l16;
            float bias = b01[d];
            #pragma unroll
            for (int r = 0; r < 4; ++r) {
                int px = ii * 32 + t * 16 + quad * 4 + r;
                H1[px * 136 + d] = (f16)fmaxf(acc[t][n][r] + bias, 0.f);
            }
        }

    f32x4 acc2[2][4];
    #pragma unroll
    for (int t = 0; t < 2; ++t)
        #pragma unroll
        for (int n = 0; n < 4; ++n) acc2[t][n] = zero;

    for (int c0 = 0; c0 < 128; c0 += 32) {
        __syncthreads();
        {
            int d = tid >> 2, q = tid & 3;
            if (d < 64)
                *(uint4*)(BW + d * 40 + q * 8) =
                    *(const uint4*)(w02t + (size_t)d * 128 + c0 + q * 8);
        }
        __syncthreads();
        half8 a0 = *(const half8*)(H1 + (ii * 32 + l16) * 136 + c0 + quad * 8);
        half8 a1 = *(const half8*)(H1 + (ii * 32 + 16 + l16) * 136 + c0 + quad * 8);
        #pragma unroll
        for (int n = 0; n < 4; ++n) {
            half8 bf = *(const half8*)(BW + (n * 16 + l16) * 40 + quad * 8);
            acc2[0][n] = __builtin_amdgcn_mfma_f32_16x16x32_f16(a0, bf, acc2[0][n], 0, 0, 0);
            acc2[1][n] = __builtin_amdgcn_mfma_f32_16x16x32_f16(a1, bf, acc2[1][n], 0, 0, 0);
        }
    }
    #pragma unroll
    for (int t = 0; t < 2; ++t)
        #pragma unroll
        for (int n = 0; n < 4; ++n) {
            int e = n * 16 + l16;
            float bias = b02[e];
            #pragma unroll
            for (int r = 0; r < 4; ++r) {
                int px = ii * 32 + t * 16 + quad * 4 + r;
                H2[px * 72 + e] = (f16)fmaxf(acc2[t][n][r] + bias, 0.f);
            }
        }
    __syncthreads();
    if (tid < 128) {
        int px = tid;
        float s = b03[0];
        const f16* h = H2 + px * 72;
        #pragma unroll 8
        for (int c = 0; c < 64; ++c) s += (float)h[c] * W3s[c];
        int i = i0 + (px >> 5), j = j0 + (px & 31);
        if (j < N_TOK)
            X0[(size_t)b * NPX + i * N_TOK + j] = fmaxf(s, 0.f);
    }
}

// ---------------------------------------------------------------------------
// Symmetrize + softmax over 38416 logits, /2 folded in.
// ---------------------------------------------------------------------------
__global__ __launch_bounds__(1024) void symsoftmax(float* __restrict__ X0,
                                                   float* __restrict__ X1)
{
    __shared__ float red[32];
    __shared__ float red2[32];
    float* X = (blockIdx.y ? X1 : X0) + (long long)blockIdx.x * NPX;
    int tid = threadIdx.x;
    float v[38];
    float mx = -3.0e38f;
    #pragma unroll
    for (int p = 0; p < 38; ++p) {
        int e = tid + p * 1024;
        if (e < NPX) {
            int i = e / 196, j = e - i * 196;
            float t = X[e] + X[j * 196 + i];
            v[p] = t;
            mx = fmaxf(mx, t);
        } else v[p] = -3.0e38f;
    }
    #pragma unroll
    for (int off = 32; off > 0; off >>= 1) mx = fmaxf(mx, __shfl_xor(mx, off));
    if ((tid & 63) == 0) red[tid >> 6] = mx;
    __syncthreads();
    if (tid < 64) {
        float m = (tid < 16) ? red[tid] : -3.0e38f;
        #pragma unroll
        for (int off = 8; off > 0; off >>= 1) m = fmaxf(m, __shfl_xor(m, off));
        if (tid == 0) red[0] = m;
    }
    __syncthreads();
    mx = red[0];
    float s = 0.f;
    #pragma unroll
    for (int p = 0; p < 38; ++p) {
        int e = tid + p * 1024;
        float ex = (e < NPX) ? expf(v[p] - mx) : 0.f;
        v[p] = ex;
        s += ex;
    }
    #pragma unroll
    for (int off = 32; off > 0; off >>= 1) s += __shfl_xor(s, off);
    if ((tid & 63) == 0) red2[tid >> 6] = s;
    __syncthreads();
    if (tid < 64) {
        float m = (tid < 16) ? red2[tid] : 0.f;
        #pragma unroll
        for (int off = 8; off > 0; off >>= 1) m += __shfl_xor(m, off);
        if (tid == 0) red2[0] = m;
    }
    __syncthreads();
    float scale = 0.5f / red2[0];
    #pragma unroll
    for (int p = 0; p < 38; ++p) {
        int e = tid + p * 1024;
        if (e < NPX) X[e] = v[p] * scale;
    }
}

// Ph[b][i][200] = fp16( (X0+X1) * 512 ), row-padded with zeros
__global__ void combine_ph(const float* __restrict__ X0,
                           const float* __restrict__ X1,
                           f16* __restrict__ Ph)
{
    int e = blockIdx.x * 256 + threadIdx.x;
    if (e >= 8 * 196 * 200) return;
    int j = e % 200;
    int row = e / 200;
    f16 v = (f16)0.f;
    if (j < 196) {
        int src = row * 196 + j;
        v = (f16)((X0[src] + X1[src]) * 512.0f);
    }
    Ph[e] = v;
}

// ---------------------------------------------------------------------------
// out[b] = (Ph[b]/512) @ x[b] via fp16 MFMA. grid (16, 4, 8).
// ---------------------------------------------------------------------------
__global__ __launch_bounds__(256, 2) void gemm_out(
    const f16* __restrict__ Ph, const f16* __restrict__ xht,
    float* __restrict__ out)
{
    __shared__ f16 As[64 * 72];
    __shared__ f16 Bs[128 * 72];
    int b = blockIdx.z;
    int n0 = blockIdx.x * 128, m0 = blockIdx.y * 64;
    int tid = threadIdx.x;
    const f16* Pb = Ph + (size_t)b * 196 * 200;
    const f16* xb = xht + (size_t)b * 2048 * 200;

    int wave = tid >> 6, lane = tid & 63;
    int quad = lane >> 4, l16 = lane & 15;

    f32x4 zero = {0.f, 0.f, 0.f, 0.f};
    f32x4 acc[8];
    #pragma unroll
    for (int n = 0; n < 8; ++n) acc[n] = zero;

    uint4 zz = make_uint4(0, 0, 0, 0);
    for (int k0 = 0; k0 < 256; k0 += 64) {
        __syncthreads();
        for (int e = tid; e < 512; e += 256) {
            int r = e >> 3, q = e & 7;
            int gm = m0 + r, k = k0 + q * 8;
            uint4 v = zz;
            if (gm < 196 && k < 200) v = *(const uint4*)(Pb + (size_t)gm * 200 + k);
            *(uint4*)(As + r * 72 + q * 8) = v;
        }
        for (int e = tid; e < 1024; e += 256) {
            int r = e >> 3, q = e & 7;
            int k = k0 + q * 8;
            uint4 v = zz;
            if (k < 200) v = *(const uint4*)(xb + (size_t)(n0 + r) * 200 + k);
            *(uint4*)(Bs + r * 72 + q * 8) = v;
        }
        __syncthreads();
        #pragma unroll
        for (int ks = 0; ks < 2; ++ks) {
            half8 a = *(const half8*)(As + (wave * 16 + l16) * 72 + ks * 32 + quad * 8);
            #pragma unroll
            for (int n = 0; n < 8; ++n) {
                half8 bf = *(const half8*)(Bs + (n * 16 + l16) * 72 + ks * 32 + quad * 8);
                acc[n] = __builtin_amdgcn_mfma_f32_16x16x32_f16(a, bf, acc[n], 0, 0, 0);
            }
        }
    }
    int m_base = m0 + wave * 16 + quad * 4;
    float* ob = out + (size_t)b * 196 * 2048;
    #pragma unroll
    for (int n = 0; n < 8; ++n) {
        int gn = n0 + n * 16 + l16;
        #pragma unroll
        for (int r = 0; r < 4; ++r) {
            int gm = m_base + r;
            if (gm < 196) ob[(size_t)gm * 2048 + gn] = acc[n][r] * (1.0f / 512.0f);
        }
    }
}

// ---------------------------------------------------------------------------
extern "C" void kernel_launch(void* const* d_in, const int* in_sizes, int n_in,
                              void* d_out, int out_size, void* d_ws, size_t ws_size,
                              hipStream_t stream)
{
    (void)in_sizes; (void)n_in; (void)out_size; (void)ws_size;
    const float* x     = (const float*)d_in[0];
    const float* w_prj = (const float*)d_in[1];
    const float* b_prj = (const float*)d_in[2];
    const float* w01   = (const float*)d_in[3];
    const float* b01   = (const float*)d_in[4];
    const float* w02   = (const float*)d_in[5];
    const float* b02   = (const float*)d_in[6];
    const float* w03   = (const float*)d_in[7];
    const float* b03   = (const float*)d_in[8];
    const float* w1    = (const float*)d_in[9];
    const float* b1    = (const float*)d_in[10];
    const float* w2    = (const float*)d_in[11];
    const float* b2    = (const float*)d_in[12];
    const float* w3    = (const float*)d_in[13];
    const float* b3    = (const float*)d_in[14];

    char* W = (char*)d_ws;
    float* part = (float*)(W + 0);          // 8*401408 f = 12.85 MB
    float* X0   = (float*)(W + 12845056);   // 307328 f
    float* X1   = (float*)(W + 14074368);   // 307328 f
    f16*   subh = (f16*)(W + 15303680);     // 401408 h
    f16*   w1f  = (f16*)(W + 16106496);     // 294912 h (frag-packed)
    f16*   w2f  = (f16*)(W + 16696320);     // 73728 h (frag-packed)
    f16*   w01t = (f16*)(W + 16843776);     // 32768 h
    f16*   w02t = (f16*)(W + 16909312);     // 8192 h
    f16*   Ph   = (f16*)(W + 16925696);     // 8*196*200 h
    f16*   xht  = (f16*)(W + 17552896);     // 8*2048*200 h
    f16*   Y1h  = (f16*)(W + 24106496);     // 8*38416*128 h = 78.7 MB
    f16*   Y2h  = (f16*)(W + 102782464);    // 8*38416*64 h  = 39.3 MB

    // 1. projection: fp16 MFMA split-K gemm -> partials -> reduce -> subh
    proj_mfma<<<dim3(2, 13, 8), 256, 0, stream>>>(x, w_prj, part);
    reduce_subh<<<dim3(1568), 256, 0, stream>>>(part, b_prj, subh);

    // 2. weight conversions (frag-packed for conv1/conv2) + x transpose
    cvt_wfrag<<<dim3(144), 256, 0, stream>>>(w1, w1f, 256, 128, 9);
    cvt_wfrag<<<dim3(36),  256, 0, stream>>>(w2, w2f, 128, 64, 9);
    cvt_wt<<<dim3(128),  256, 0, stream>>>(w01, w01t, 256, 128, 32768);
    cvt_wt<<<dim3(32),   256, 0, stream>>>(w02, w02t, 128, 64, 8192);
    cvt_xT<<<dim3(64, 7, 8), 256, 0, stream>>>(x, xht);

    // 3. branch 0 (MFMA) -> X0 logits
    branch0_mfma<<<dim3(7, 49, 8), 256, 0, stream>>>(
        subh, w01t, b01, w02t, b02, w03, b03, X0);

    // 4. conv branch (MFMA fp16) -> X1 logits
    conv1_mfma<<<dim3(7, 25, 8), 1024, 0, stream>>>(subh, w1f, b1, Y1h);
    conv2_mfma<<<dim3(7, 49, 8), 256, 0, stream>>>(Y1h, w2f, b2, Y2h);
    conv3_s<<<dim3(7, 25, 8), 256, 0, stream>>>(Y2h, w3, b3, X1);

    // 5. symmetrize + softmax both maps (x0.5 folded in)
    symsoftmax<<<dim3(8, 2), 1024, 0, stream>>>(X0, X1);

    // 6. Ph = (map0 + map1) * 512 as fp16
    combine_ph<<<dim3(1225), 256, 0, stream>>>(X0, X1, Ph);

    // 7. out[b] = Ph[b]/512 @ x[b]  (fp16 MFMA, fp32 accum)
    gemm_out<<<dim3(16, 4, 8), 256, 0, stream>>>(Ph, xht, (float*)d_out);
}

// Round 12
// 512.941 us; speedup vs baseline: 1.0902x; 1.0902x over previous
//
#include <hip/hip_runtime.h>
#include <cmath>

#define N_TOK 196
#define NPX   38416
#define CDIM  256

typedef _Float16 f16;
typedef __attribute__((ext_vector_type(8))) _Float16 half8;
typedef __attribute__((ext_vector_type(4))) float f32x4;

// ---------------------------------------------------------------------------
// Projection GEMM via fp16 MFMA, split-K=8. M=1568, N=256, K=2048.
// Tile 128m x 128n, K-step 32, inline fp32->f16 staging. grid (2, 13, 8).
// ---------------------------------------------------------------------------
__global__ __launch_bounds__(256) void proj_mfma(
    const float* __restrict__ A,   // x  [1568][2048]
    const float* __restrict__ B,   // w_prj [2048][256]
    float* __restrict__ P)         // [8][1568][256]
{
    __shared__ f16 As[128 * 40];   // [m][k] pad 40 (16B-aligned rows)
    __shared__ f16 Bs[128 * 40];   // [n][k] (transposed during staging)
    int tid = threadIdx.x;
    int n0 = blockIdx.x * 128, m0 = blockIdx.y * 128;
    int kz = blockIdx.z;
    int wave = tid >> 6, lane = tid & 63;
    int quad = lane >> 4, l16 = lane & 15;

    f32x4 zero = {0.f, 0.f, 0.f, 0.f};
    f32x4 acc[2][8];
    #pragma unroll
    for (int mt = 0; mt < 2; ++mt)
        #pragma unroll
        for (int nt = 0; nt < 8; ++nt) acc[mt][nt] = zero;

    for (int k0 = kz * 256; k0 < kz * 256 + 256; k0 += 32) {
        __syncthreads();
        #pragma unroll
        for (int s = 0; s < 4; ++s) {
            int idx = tid + s * 256;
            int m = idx >> 3, kq = idx & 7;
            int gm = m0 + m;
            float4 v = make_float4(0.f, 0.f, 0.f, 0.f);
            if (gm < 1568) v = *(const float4*)(A + (size_t)gm * 2048 + k0 + kq * 4);
            f16* d = As + m * 40 + kq * 4;
            d[0] = (f16)v.x; d[1] = (f16)v.y; d[2] = (f16)v.z; d[3] = (f16)v.w;
        }
        #pragma unroll
        for (int s = 0; s < 4; ++s) {
            int idx = tid + s * 256;
            int nq = idx & 31, kk = idx >> 5;
            float4 v = *(const float4*)(B + (size_t)(k0 + kk) * 256 + n0 + nq * 4);
            Bs[(nq * 4 + 0) * 40 + kk] = (f16)v.x;
            Bs[(nq * 4 + 1) * 40 + kk] = (f16)v.y;
            Bs[(nq * 4 + 2) * 40 + kk] = (f16)v.z;
            Bs[(nq * 4 + 3) * 40 + kk] = (f16)v.w;
        }
        __syncthreads();
        half8 a[2];
        #pragma unroll
        for (int mt = 0; mt < 2; ++mt)
            a[mt] = *(const half8*)(As + (wave * 32 + mt * 16 + l16) * 40 + quad * 8);
        #pragma unroll
        for (int nt = 0; nt < 8; ++nt) {
            half8 bf = *(const half8*)(Bs + (nt * 16 + l16) * 40 + quad * 8);
            acc[0][nt] = __builtin_amdgcn_mfma_f32_16x16x32_f16(a[0], bf, acc[0][nt], 0, 0, 0);
            acc[1][nt] = __builtin_amdgcn_mfma_f32_16x16x32_f16(a[1], bf, acc[1][nt], 0, 0, 0);
        }
    }
    float* Pz = P + (size_t)kz * 401408;
    #pragma unroll
    for (int mt = 0; mt < 2; ++mt) {
        #pragma unroll
        for (int nt = 0; nt < 8; ++nt) {
            int gn = n0 + nt * 16 + l16;
            #pragma unroll
            for (int r = 0; r < 4; ++r) {
                int gm = m0 + wave * 32 + mt * 16 + quad * 4 + r;
                if (gm < 1568) Pz[(size_t)gm * 256 + gn] = acc[mt][nt][r];
            }
        }
    }
}

// sum 8 K-slices + bias -> fp16 sub
__global__ void reduce_subh(const float* __restrict__ P,
                            const float* __restrict__ bias,
                            f16* __restrict__ subh)
{
    int e = blockIdx.x * 256 + threadIdx.x;
    if (e >= 401408) return;
    float s = bias[e & 255];
    #pragma unroll
    for (int z = 0; z < 8; ++z) s += P[(size_t)z * 401408 + e];
    subh[e] = (f16)s;
}

// ---------------------------------------------------------------------------
// w [tap][Kc][D] fp32 -> wt [tap][D][Kc] fp16  (plain transpose, branch0)
// ---------------------------------------------------------------------------
__global__ void cvt_wt(const float* __restrict__ w, f16* __restrict__ wt,
                       int Kc, int D, int total)
{
    int e = blockIdx.x * 256 + threadIdx.x;
    if (e >= total) return;
    int td = Kc * D;
    int tap = e / td, r = e - tap * td;
    int c = r / D, d = r - c * D;
    wt[(size_t)(tap * D + d) * Kc + c] = (f16)w[e];
}

// ---------------------------------------------------------------------------
// w [tap][Kc][D] fp32 -> MFMA B-fragment-packed fp16:
// wf[(((tap*tiles + tile)*kch + k)*64 + lane)*8 + j], lane=(quad*16+l16),
// element = w[tap][k*32 + quad*8 + j][tile*16 + l16].
// ---------------------------------------------------------------------------
__global__ void cvt_wfrag(const float* __restrict__ w, f16* __restrict__ wf,
                          int Kc, int D, int taps)
{
    int tiles = D >> 4, kch = Kc >> 5;
    int total = taps * tiles * kch * 64;
    int e = blockIdx.x * 256 + threadIdx.x;
    if (e >= total) return;
    int lane = e & 63;
    int rest = e >> 6;
    int k = rest % kch; rest /= kch;
    int tile = rest % tiles;
    int tap = rest / tiles;
    int l16 = lane & 15, quad = lane >> 4;
    const float* src = w + ((size_t)tap * Kc + k * 32 + quad * 8) * D + tile * 16 + l16;
    f16* dst = wf + (size_t)e * 8;
    #pragma unroll
    for (int j = 0; j < 8; ++j) dst[j] = (f16)src[(size_t)j * D];
}

// x [b][196][2048] fp32 -> xht [b][2048][200] fp16 (k-pad 200, zeros)
__global__ __launch_bounds__(256) void cvt_xT(const float* __restrict__ x,
                                              f16* __restrict__ xht)
{
    __shared__ float t[32][33];
    int b = blockIdx.z;
    int i0 = blockIdx.y * 32, n0 = blockIdx.x * 32;
    const float* xb = x + (size_t)b * 196 * 2048;
    for (int e = threadIdx.x; e < 1024; e += 256) {
        int r = e >> 5, c = e & 31;
        int gi = i0 + r;
        t[r][c] = (gi < 196) ? xb[(size_t)gi * 2048 + n0 + c] : 0.f;
    }
    __syncthreads();
    f16* xb2 = xht + (size_t)b * 2048 * 200;
    for (int e = threadIdx.x; e < 1024; e += 256) {
        int nl = e >> 5, il = e & 31;
        int gi = i0 + il, gn = n0 + nl;
        if (gi < 200) xb2[(size_t)gn * 200 + gi] = (f16)t[il][nl];
    }
}

// ---------------------------------------------------------------------------
// Conv1 v6 (FINAL): barrier-free K-loop, frag-packed B, dedup'd pair
// construction, per-(block,wave) k-rotation. Block 256px (8i x 32j) x 128d,
// 4 waves; wave = 128px (4i) x 64d. Verified local optimum: 32x32 MFMA (R1),
// global-weight streams (R3), and 16-wave occupancy retile (R11) all
// regressed. Register-capped at 2 waves/SIMD (120 VGPR + 128 acc).
// grid (7, 25, 8).
// ---------------------------------------------------------------------------
__global__ __launch_bounds__(256, 2) void conv1_mfma(
    const f16* __restrict__ sub_h,   // [8][196][256]
    const f16* __restrict__ w1f,     // frag-packed [9][8][8][64][8]
    const float* __restrict__ b1,    // [128]
    f16* __restrict__ Y1h)           // [8][196][196][128]
{
    __shared__ f16 sh[17408];        // 34816 B
    f16* SJ = sh;                    // [34][264] rows j0-1..j0+32
    f16* SI = sh + 8976;             // [10][264] rows i0-1..i0+8
    f16* OT = sh;                    // epilogue [128][136] (aliases SJ/SI)

    int b = blockIdx.z;
    int i0 = blockIdx.y * 8, j0 = blockIdx.x * 32;
    int tid = threadIdx.x;
    const f16* subB = sub_h + (size_t)b * N_TOK * CDIM;

    uint4 zz = make_uint4(0, 0, 0, 0);
    for (int e = tid; e < 1088; e += 256) {       // SJ
        int r = e >> 5, q = e & 31;
        int gj = j0 - 1 + r;
        uint4 v = zz;
        if (gj >= 0 && gj < N_TOK) v = *(const uint4*)(subB + gj * CDIM + q * 8);
        *(uint4*)(SJ + r * 264 + q * 8) = v;
    }
    for (int e = tid; e < 320; e += 256) {        // SI
        int r = e >> 5, q = e & 31;
        int gi = i0 - 1 + r;
        uint4 v = zz;
        if (gi >= 0 && gi < N_TOK) v = *(const uint4*)(subB + gi * CDIM + q * 8);
        *(uint4*)(SI + r * 264 + q * 8) = v;
    }
    __syncthreads();

    int wave = tid >> 6, lane = tid & 63;
    int quad = lane >> 4, l16 = lane & 15;
    int p  = wave >> 1;          // px half: i base = p*4
    int dh = wave & 1;           // d half: d0 = dh*64
    int d0 = dh * 64;

    float bias_r[4];
    #pragma unroll
    for (int n = 0; n < 4; ++n) bias_r[n] = b1[d0 + n * 16 + l16];

    // frag strides (halfs): lane 8, k 512, tile 4096, tap 32768
    const f16* wbase = w1f + (size_t)lane * 8 + (size_t)dh * 4 * 4096;

    // per-(block,wave) k-phase rotation (uniform scalar; bijective over k)
    int lb = blockIdx.x + 7 * (blockIdx.y + 25 * blockIdx.z);
    int rot = (lb * 3 + wave) & 7;

    f32x4 zero = {0.f, 0.f, 0.f, 0.f};
    f32x4 acc[8][4];
    #pragma unroll
    for (int m = 0; m < 8; ++m)
        #pragma unroll
        for (int n = 0; n < 4; ++n) acc[m][n] = zero;

    for (int kk = 0; kk < 8; ++kk) {
        int k = (kk + rot) & 7;
        int c0 = k * 32;
        half8 si[6];
        #pragma unroll
        for (int r = 0; r < 6; ++r)
            si[r] = *(const half8*)(SI + (p * 4 + r) * 264 + c0 + quad * 8);
        half8 sj[2][3];
        #pragma unroll
        for (int jf = 0; jf < 2; ++jf)
            #pragma unroll
            for (int dd = 0; dd < 3; ++dd)
                sj[jf][dd] = *(const half8*)(SJ + (jf * 16 + l16 + dd) * 264 + c0 + quad * 8);

        #pragma unroll
        for (int dj = 0; dj < 3; ++dj) {
            half8 bf[3][4];
            #pragma unroll
            for (int di = 0; di < 3; ++di)
                #pragma unroll
                for (int n = 0; n < 4; ++n)
                    bf[di][n] = *(const half8*)(wbase + (size_t)(di * 3 + dj) * 32768
                                                + n * 4096 + k * 512);
            #pragma unroll
            for (int r = 0; r < 6; ++r) {
                half8 a0 = si[r] * sj[0][dj];
                half8 a1 = si[r] * sj[1][dj];
                #pragma unroll
                for (int di = 0; di < 3; ++di) {
                    int i = r - di;
                    if (i < 0 || i > 3) continue;
                    #pragma unroll
                    for (int n = 0; n < 4; ++n) {
                        acc[i * 2 + 0][n] = __builtin_amdgcn_mfma_f32_16x16x32_f16(
                            a0, bf[di][n], acc[i * 2 + 0][n], 0, 0, 0);
                        acc[i * 2 + 1][n] = __builtin_amdgcn_mfma_f32_16x16x32_f16(
                            a1, bf[di][n], acc[i * 2 + 1][n], 0, 0, 0);
                    }
                }
            }
        }
    }

    // epilogue: two px-half phases through OT (aliases SJ/SI)
    __syncthreads();
    f16* Yb = Y1h + (size_t)b * NPX * 128;
    #pragma unroll
    for (int ph = 0; ph < 2; ++ph) {
        if (p == ph) {
            #pragma unroll
            for (int i = 0; i < 4; ++i)
                #pragma unroll
                for (int jf = 0; jf < 2; ++jf) {
                    int m = i * 2 + jf;
                    #pragma unroll
                    for (int n = 0; n < 4; ++n) {
                        int dl = d0 + n * 16 + l16;
                        #pragma unroll
                        for (int r = 0; r < 4; ++r) {
                            int pxl = i * 32 + jf * 16 + quad * 4 + r;
                            OT[pxl * 136 + dl] = (f16)fmaxf(acc[m][n][r] + bias_r[n], 0.f);
                        }
                    }
                }
        }
        __syncthreads();
        for (int e = tid; e < 2048; e += 256) {
            int pxl = e >> 4, q = e & 15;
            int gi = i0 + ph * 4 + (pxl >> 5), gj = j0 + (pxl & 31);
            if (gi < N_TOK && gj < N_TOK)
                *(uint4*)(Yb + ((size_t)gi * N_TOK + gj) * 128 + q * 8) =
                    *(const uint4*)(OT + pxl * 136 + q * 8);
        }
        __syncthreads();
    }
}

// ---------------------------------------------------------------------------
// Conv2 v3: 3x3 dil (1,2), 128->64, frag-packed B, barrier-free K-loop.
// Tile 128px (4i x 32j) x 64d, 4 waves; wave = 1 i-row x 32j (2 j-frags).
// Halo read-amplification 1.69x. grid (7, 49, 8).
// ---------------------------------------------------------------------------
__global__ __launch_bounds__(256, 2) void conv2_mfma(
    const f16* __restrict__ Y1h, const f16* __restrict__ w2f,
    const float* __restrict__ b2, f16* __restrict__ Y2h)
{
    __shared__ f16 sh[29376];        // [6][36][136] = 58752 B
    f16* Ys = sh;
    f16* OT = sh;                    // epilogue [128][72] (aliases Ys)

    int b = blockIdx.z;
    int i0 = blockIdx.y * 4, j0 = blockIdx.x * 32;
    int tid = threadIdx.x;
    const f16* Yb = Y1h + (size_t)b * NPX * 128;

    uint4 zz = make_uint4(0, 0, 0, 0);
    for (int e = tid; e < 3456; e += 256) {
        int ir = e / 576, rem = e - ir * 576;
        int jq = rem >> 4, q = rem & 15;
        int gi = i0 - 1 + ir, gj = j0 - 2 + jq;
        uint4 v = zz;
        if (gi >= 0 && gi < N_TOK && gj >= 0 && gj < N_TOK)
            v = *(const uint4*)(Yb + ((size_t)gi * N_TOK + gj) * 128 + q * 8);
        *(uint4*)(Ys + (ir * 36 + jq) * 136 + q * 8) = v;
    }
    __syncthreads();

    int wave = tid >> 6, lane = tid & 63;
    int quad = lane >> 4, l16 = lane & 15;
    int ii = wave;                   // i-row within tile

    // frag strides (halfs): lane 8, k 512, tile 2048, tap 8192
    const f16* wbase = w2f + (size_t)lane * 8;

    f32x4 zero = {0.f, 0.f, 0.f, 0.f};
    f32x4 acc[2][4];
    #pragma unroll
    for (int jf = 0; jf < 2; ++jf)
        #pragma unroll
        for (int n = 0; n < 4; ++n) acc[jf][n] = zero;

    #pragma unroll
    for (int tap = 0; tap < 9; ++tap) {
        int di = tap / 3 - 1, dj2 = (tap % 3 - 1) * 2;
        #pragma unroll
        for (int k = 0; k < 4; ++k) {
            int c0 = k * 32;
            half8 a0 = *(const half8*)(Ys + ((ii + di + 1) * 36 + l16 + dj2 + 2) * 136
                                       + c0 + quad * 8);
            half8 a1 = *(const half8*)(Ys + ((ii + di + 1) * 36 + 16 + l16 + dj2 + 2) * 136
                                       + c0 + quad * 8);
            #pragma unroll
            for (int n = 0; n < 4; ++n) {
                half8 bf = *(const half8*)(wbase + (size_t)tap * 8192 + n * 2048 + k * 512);
                acc[0][n] = __builtin_amdgcn_mfma_f32_16x16x32_f16(a0, bf, acc[0][n], 0, 0, 0);
                acc[1][n] = __builtin_amdgcn_mfma_f32_16x16x32_f16(a1, bf, acc[1][n], 0, 0, 0);
            }
        }
    }
    __syncthreads();
    #pragma unroll
    for (int jf = 0; jf < 2; ++jf)
        #pragma unroll
        for (int n = 0; n < 4; ++n) {
            int d = n * 16 + l16;
            float bias = b2[d];
            #pragma unroll
            for (int r = 0; r < 4; ++r) {
                int px = ii * 32 + jf * 16 + quad * 4 + r;
                OT[px * 72 + d] = (f16)fmaxf(acc[jf][n][r] + bias, 0.f);
            }
        }
    __syncthreads();
    f16* Zb = Y2h + (size_t)b * NPX * 64;
    for (int e = tid; e < 1024; e += 256) {
        int px = e >> 3, q = e & 7;
        int i = i0 + (px >> 5), j = j0 + (px & 31);
        if (j < N_TOK)
            *(uint4*)(Zb + ((size_t)i * N_TOK + j) * 64 + q * 8) =
                *(const uint4*)(OT + px * 72 + q * 8);
    }
}

// ---------------------------------------------------------------------------
// Conv3 v2: LDS-staged. Block = 8i x 32j px, halo'd tile [10][40][64] (pad 68).
// Lanes split 8-per-px over c (2-way bank aliasing = free), shfl reduce.
// grid (7, 25, 8).
// ---------------------------------------------------------------------------
__global__ __launch_bounds__(256) void conv3_s(
    const f16* __restrict__ Y2h, const float* __restrict__ w3,
    const float* __restrict__ b3, float* __restrict__ X1)
{
    __shared__ f16 Ys[10 * 40 * 68];   // 54400 B
    __shared__ float ws[576];
    int b = blockIdx.z;
    int i0 = blockIdx.y * 8, j0 = blockIdx.x * 32;
    int tid = threadIdx.x;
    const f16* Yb = Y2h + (size_t)b * NPX * 64;
    for (int e = tid; e < 576; e += 256) ws[e] = w3[e];
    uint4 zz = make_uint4(0, 0, 0, 0);
    for (int e = tid; e < 3200; e += 256) {
        int r = e / 320, rem = e - r * 320;
        int jq = rem >> 3, q = rem & 7;
        int gi = i0 - 1 + r, gj = j0 - 4 + jq;
        uint4 v = zz;
        if (gi >= 0 && gi < N_TOK && gj >= 0 && gj < N_TOK)
            v = *(const uint4*)(Yb + ((size_t)gi * N_TOK + gj) * 64 + q * 8);
        *(uint4*)(Ys + (r * 40 + jq) * 68 + q * 8) = v;
    }
    __syncthreads();
    int q = tid & 7, jl = (tid >> 3) & 31;
    float* Xb = X1 + (size_t)b * NPX;
    float bb = b3[0];
    #pragma unroll
    for (int il = 0; il < 8; ++il) {
        float s = 0.f;
        #pragma unroll
        for (int tap = 0; tap < 9; ++tap) {
            int di = tap / 3 - 1, dj4 = (tap % 3 - 1) * 4;
            half8 h = *(const half8*)(Ys + ((il + 1 + di) * 40 + jl + 4 + dj4) * 68 + q * 8);
            #pragma unroll
            for (int e = 0; e < 8; ++e) s += (float)h[e] * ws[tap * 64 + q * 8 + e];
        }
        s += __shfl_xor(s, 1);
        s += __shfl_xor(s, 2);
        s += __shfl_xor(s, 4);
        if (q == 0) {
            int gi = i0 + il, gj = j0 + jl;
            if (gi < N_TOK && gj < N_TOK)
                Xb[gi * N_TOK + gj] = fmaxf(s + bb, 0.f);
        }
    }
}

// ---------------------------------------------------------------------------
// Branch 0 MFMA: pair -> 1x1 stack 256->128->64->1, all in one block.
// ---------------------------------------------------------------------------
__global__ __launch_bounds__(256, 2) void branch0_mfma(
    const f16* __restrict__ sub_h,
    const f16* __restrict__ w01t,    // [128][256]
    const float* __restrict__ b01,
    const f16* __restrict__ w02t,    // [64][128]
    const float* __restrict__ b02,
    const float* __restrict__ w03, const float* __restrict__ b03,
    float* __restrict__ X0)
{
    __shared__ f16 sh[32000];
    __shared__ float W3s[64];
    f16* SJ = sh;            // [32][264]
    f16* SI = sh + 8448;     // [4][256]
    f16* BW = sh + 9472;     // [128][40]
    f16* H1 = sh + 14592;    // [128][136]
    f16* H2 = sh;            // [128][72] (aliases SJ/SI)

    int b = blockIdx.z;
    int i0 = blockIdx.y * 4, j0 = blockIdx.x * 32;
    int tid = threadIdx.x;
    const f16* subB = sub_h + (size_t)b * N_TOK * CDIM;

    uint4 zz = make_uint4(0, 0, 0, 0);
    for (int e = tid; e < 1024; e += 256) {
        int r = e >> 5, q = e & 31;
        int gj = j0 + r;
        uint4 v = zz;
        if (gj < N_TOK) v = *(const uint4*)(subB + gj * CDIM + q * 8);
        *(uint4*)(SJ + r * 264 + q * 8) = v;
    }
    if (tid < 128) {
        int r = tid >> 5, q = tid & 31;
        int gi = i0 + r;
        uint4 v = zz;
        if (gi < N_TOK) v = *(const uint4*)(subB + gi * CDIM + q * 8);
        *(uint4*)(SI + r * 256 + q * 8) = v;
    }
    if (tid < 64) W3s[tid] = w03[tid];

    int wave = tid >> 6, lane = tid & 63;
    int quad = lane >> 4, l16 = lane & 15;
    int ii = wave;

    f32x4 zero = {0.f, 0.f, 0.f, 0.f};
    f32x4 acc[2][8];
    #pragma unroll
    for (int t = 0; t < 2; ++t)
        #pragma unroll
        for (int n = 0; n < 8; ++n) acc[t][n] = zero;

    for (int c0 = 0; c0 < 256; c0 += 32) {
        __syncthreads();
        for (int e = tid; e < 512; e += 256) {
            int d = e >> 2, q = e & 3;
            *(uint4*)(BW + d * 40 + q * 8) =
                *(const uint4*)(w01t + (size_t)d * 256 + c0 + q * 8);
        }
        __syncthreads();
        half8 sib = *(const half8*)(SI + ii * 256 + c0 + quad * 8);
        half8 a0 = sib * *(const half8*)(SJ + l16 * 264 + c0 + quad * 8);
        half8 a1 = sib * *(const half8*)(SJ + (l16 + 16) * 264 + c0 + quad * 8);
        #pragma unroll
        for (int n = 0; n < 8; ++n) {
            half8 bf = *(const half8*)(BW + (n * 16 + l16) * 40 + quad * 8);
            acc[0][n] = __builtin_amdgcn_mfma_f32_16x16x32_f16(a0, bf, acc[0][n], 0, 0, 0);
            acc[1][n] = __builtin_amdgcn_mfma_f32_16x16x32_f16(a1, bf, acc[1][n], 0, 0, 0);
        }
    }
    #pragma unroll
    for (int t = 0; t < 2; ++t)
        #pragma unroll
        for (int n = 0; n < 8; ++n) {
            int d = n * 16 + l16;
            float bias = b01[d];
            #pragma unroll
            for (int r = 0; r < 4; ++r) {
                int px = ii * 32 + t * 16 + quad * 4 + r;
                H1[px * 136 + d] = (f16)fmaxf(acc[t][n][r] + bias, 0.f);
            }
        }

    f32x4 acc2[2][4];
    #pragma unroll
    for (int t = 0; t < 2; ++t)
        #pragma unroll
        for (int n = 0; n < 4; ++n) acc2[t][n] = zero;

    for (int c0 = 0; c0 < 128; c0 += 32) {
        __syncthreads();
        {
            int d = tid >> 2, q = tid & 3;
            if (d < 64)
                *(uint4*)(BW + d * 40 + q * 8) =
                    *(const uint4*)(w02t + (size_t)d * 128 + c0 + q * 8);
        }
        __syncthreads();
        half8 a0 = *(const half8*)(H1 + (ii * 32 + l16) * 136 + c0 + quad * 8);
        half8 a1 = *(const half8*)(H1 + (ii * 32 + 16 + l16) * 136 + c0 + quad * 8);
        #pragma unroll
        for (int n = 0; n < 4; ++n) {
            half8 bf = *(const half8*)(BW + (n * 16 + l16) * 40 + quad * 8);
            acc2[0][n] = __builtin_amdgcn_mfma_f32_16x16x32_f16(a0, bf, acc2[0][n], 0, 0, 0);
            acc2[1][n] = __builtin_amdgcn_mfma_f32_16x16x32_f16(a1, bf, acc2[1][n], 0, 0, 0);
        }
    }
    #pragma unroll
    for (int t = 0; t < 2; ++t)
        #pragma unroll
        for (int n = 0; n < 4; ++n) {
            int e = n * 16 + l16;
            float bias = b02[e];
            #pragma unroll
            for (int r = 0; r < 4; ++r) {
                int px = ii * 32 + t * 16 + quad * 4 + r;
                H2[px * 72 + e] = (f16)fmaxf(acc2[t][n][r] + bias, 0.f);
            }
        }
    __syncthreads();
    if (tid < 128) {
        int px = tid;
        float s = b03[0];
        const f16* h = H2 + px * 72;
        #pragma unroll 8
        for (int c = 0; c < 64; ++c) s += (float)h[c] * W3s[c];
        int i = i0 + (px >> 5), j = j0 + (px & 31);
        if (j < N_TOK)
            X0[(size_t)b * NPX + i * N_TOK + j] = fmaxf(s, 0.f);
    }
}

// ---------------------------------------------------------------------------
// Symmetrize + softmax over 38416 logits, /2 folded in.
// ---------------------------------------------------------------------------
__global__ __launch_bounds__(1024) void symsoftmax(float* __restrict__ X0,
                                                   float* __restrict__ X1)
{
    __shared__ float red[32];
    __shared__ float red2[32];
    float* X = (blockIdx.y ? X1 : X0) + (long long)blockIdx.x * NPX;
    int tid = threadIdx.x;
    float v[38];
    float mx = -3.0e38f;
    #pragma unroll
    for (int p = 0; p < 38; ++p) {
        int e = tid + p * 1024;
        if (e < NPX) {
            int i = e / 196, j = e - i * 196;
            float t = X[e] + X[j * 196 + i];
            v[p] = t;
            mx = fmaxf(mx, t);
        } else v[p] = -3.0e38f;
    }
    #pragma unroll
    for (int off = 32; off > 0; off >>= 1) mx = fmaxf(mx, __shfl_xor(mx, off));
    if ((tid & 63) == 0) red[tid >> 6] = mx;
    __syncthreads();
    if (tid < 64) {
        float m = (tid < 16) ? red[tid] : -3.0e38f;
        #pragma unroll
        for (int off = 8; off > 0; off >>= 1) m = fmaxf(m, __shfl_xor(m, off));
        if (tid == 0) red[0] = m;
    }
    __syncthreads();
    mx = red[0];
    float s = 0.f;
    #pragma unroll
    for (int p = 0; p < 38; ++p) {
        int e = tid + p * 1024;
        float ex = (e < NPX) ? expf(v[p] - mx) : 0.f;
        v[p] = ex;
        s += ex;
    }
    #pragma unroll
    for (int off = 32; off > 0; off >>= 1) s += __shfl_xor(s, off);
    if ((tid & 63) == 0) red2[tid >> 6] = s;
    __syncthreads();
    if (tid < 64) {
        float m = (tid < 16) ? red2[tid] : 0.f;
        #pragma unroll
        for (int off = 8; off > 0; off >>= 1) m += __shfl_xor(m, off);
        if (tid == 0) red2[0] = m;
    }
    __syncthreads();
    float scale = 0.5f / red2[0];
    #pragma unroll
    for (int p = 0; p < 38; ++p) {
        int e = tid + p * 1024;
        if (e < NPX) X[e] = v[p] * scale;
    }
}

// Ph[b][i][200] = fp16( (X0+X1) * 512 ), row-padded with zeros
__global__ void combine_ph(const float* __restrict__ X0,
                           const float* __restrict__ X1,
                           f16* __restrict__ Ph)
{
    int e = blockIdx.x * 256 + threadIdx.x;
    if (e >= 8 * 196 * 200) return;
    int j = e % 200;
    int row = e / 200;
    f16 v = (f16)0.f;
    if (j < 196) {
        int src = row * 196 + j;
        v = (f16)((X0[src] + X1[src]) * 512.0f);
    }
    Ph[e] = v;
}

// ---------------------------------------------------------------------------
// out[b] = (Ph[b]/512) @ x[b] via fp16 MFMA. grid (16, 4, 8).
// ---------------------------------------------------------------------------
__global__ __launch_bounds__(256, 2) void gemm_out(
    const f16* __restrict__ Ph, const f16* __restrict__ xht,
    float* __restrict__ out)
{
    __shared__ f16 As[64 * 72];
    __shared__ f16 Bs[128 * 72];
    int b = blockIdx.z;
    int n0 = blockIdx.x * 128, m0 = blockIdx.y * 64;
    int tid = threadIdx.x;
    const f16* Pb = Ph + (size_t)b * 196 * 200;
    const f16* xb = xht + (size_t)b * 2048 * 200;

    int wave = tid >> 6, lane = tid & 63;
    int quad = lane >> 4, l16 = lane & 15;

    f32x4 zero = {0.f, 0.f, 0.f, 0.f};
    f32x4 acc[8];
    #pragma unroll
    for (int n = 0; n < 8; ++n) acc[n] = zero;

    uint4 zz = make_uint4(0, 0, 0, 0);
    for (int k0 = 0; k0 < 256; k0 += 64) {
        __syncthreads();
        for (int e = tid; e < 512; e += 256) {
            int r = e >> 3, q = e & 7;
            int gm = m0 + r, k = k0 + q * 8;
            uint4 v = zz;
            if (gm < 196 && k < 200) v = *(const uint4*)(Pb + (size_t)gm * 200 + k);
            *(uint4*)(As + r * 72 + q * 8) = v;
        }
        for (int e = tid; e < 1024; e += 256) {
            int r = e >> 3, q = e & 7;
            int k = k0 + q * 8;
            uint4 v = zz;
            if (k < 200) v = *(const uint4*)(xb + (size_t)(n0 + r) * 200 + k);
            *(uint4*)(Bs + r * 72 + q * 8) = v;
        }
        __syncthreads();
        #pragma unroll
        for (int ks = 0; ks < 2; ++ks) {
            half8 a = *(const half8*)(As + (wave * 16 + l16) * 72 + ks * 32 + quad * 8);
            #pragma unroll
            for (int n = 0; n < 8; ++n) {
                half8 bf = *(const half8*)(Bs + (n * 16 + l16) * 72 + ks * 32 + quad * 8);
                acc[n] = __builtin_amdgcn_mfma_f32_16x16x32_f16(a, bf, acc[n], 0, 0, 0);
            }
        }
    }
    int m_base = m0 + wave * 16 + quad * 4;
    float* ob = out + (size_t)b * 196 * 2048;
    #pragma unroll
    for (int n = 0; n < 8; ++n) {
        int gn = n0 + n * 16 + l16;
        #pragma unroll
        for (int r = 0; r < 4; ++r) {
            int gm = m_base + r;
            if (gm < 196) ob[(size_t)gm * 2048 + gn] = acc[n][r] * (1.0f / 512.0f);
        }
    }
}

// ---------------------------------------------------------------------------
extern "C" void kernel_launch(void* const* d_in, const int* in_sizes, int n_in,
                              void* d_out, int out_size, void* d_ws, size_t ws_size,
                              hipStream_t stream)
{
    (void)in_sizes; (void)n_in; (void)out_size; (void)ws_size;
    const float* x     = (const float*)d_in[0];
    const float* w_prj = (const float*)d_in[1];
    const float* b_prj = (const float*)d_in[2];
    const float* w01   = (const float*)d_in[3];
    const float* b01   = (const float*)d_in[4];
    const float* w02   = (const float*)d_in[5];
    const float* b02   = (const float*)d_in[6];
    const float* w03   = (const float*)d_in[7];
    const float* b03   = (const float*)d_in[8];
    const float* w1    = (const float*)d_in[9];
    const float* b1    = (const float*)d_in[10];
    const float* w2    = (const float*)d_in[11];
    const float* b2    = (const float*)d_in[12];
    const float* w3    = (const float*)d_in[13];
    const float* b3    = (const float*)d_in[14];

    char* W = (char*)d_ws;
    float* part = (float*)(W + 0);          // 8*401408 f = 12.85 MB
    float* X0   = (float*)(W + 12845056);   // 307328 f
    float* X1   = (float*)(W + 14074368);   // 307328 f
    f16*   subh = (f16*)(W + 15303680);     // 401408 h
    f16*   w1f  = (f16*)(W + 16106496);     // 294912 h (frag-packed)
    f16*   w2f  = (f16*)(W + 16696320);     // 73728 h (frag-packed)
    f16*   w01t = (f16*)(W + 16843776);     // 32768 h
    f16*   w02t = (f16*)(W + 16909312);     // 8192 h
    f16*   Ph   = (f16*)(W + 16925696);     // 8*196*200 h
    f16*   xht  = (f16*)(W + 17552896);     // 8*2048*200 h
    f16*   Y1h  = (f16*)(W + 24106496);     // 8*38416*128 h = 78.7 MB
    f16*   Y2h  = (f16*)(W + 102782464);    // 8*38416*64 h  = 39.3 MB

    // 1. projection: fp16 MFMA split-K gemm -> partials -> reduce -> subh
    proj_mfma<<<dim3(2, 13, 8), 256, 0, stream>>>(x, w_prj, part);
    reduce_subh<<<dim3(1568), 256, 0, stream>>>(part, b_prj, subh);

    // 2. weight conversions (frag-packed for conv1/conv2) + x transpose
    cvt_wfrag<<<dim3(144), 256, 0, stream>>>(w1, w1f, 256, 128, 9);
    cvt_wfrag<<<dim3(36),  256, 0, stream>>>(w2, w2f, 128, 64, 9);
    cvt_wt<<<dim3(128),  256, 0, stream>>>(w01, w01t, 256, 128, 32768);
    cvt_wt<<<dim3(32),   256, 0, stream>>>(w02, w02t, 128, 64, 8192);
    cvt_xT<<<dim3(64, 7, 8), 256, 0, stream>>>(x, xht);

    // 3. branch 0 (MFMA) -> X0 logits
    branch0_mfma<<<dim3(7, 49, 8), 256, 0, stream>>>(
        subh, w01t, b01, w02t, b02, w03, b03, X0);

    // 4. conv branch (MFMA fp16) -> X1 logits
    conv1_mfma<<<dim3(7, 25, 8), 256, 0, stream>>>(subh, w1f, b1, Y1h);
    conv2_mfma<<<dim3(7, 49, 8), 256, 0, stream>>>(Y1h, w2f, b2, Y2h);
    conv3_s<<<dim3(7, 25, 8), 256, 0, stream>>>(Y2h, w3, b3, X1);

    // 5. symmetrize + softmax both maps (x0.5 folded in)
    symsoftmax<<<dim3(8, 2), 1024, 0, stream>>>(X0, X1);

    // 6. Ph = (map0 + map1) * 512 as fp16
    combine_ph<<<dim3(1225), 256, 0, stream>>>(X0, X1, Ph);

    // 7. out[b] = Ph[b]/512 @ x[b]  (fp16 MFMA, fp32 accum)
    gemm_out<<<dim3(16, 4, 8), 256, 0, stream>>>(Ph, xht, (float*)d_out);
}